// Round 4
// baseline (523.744 us; speedup 1.0000x reference)
//
#include <hip/hip_runtime.h>
#include <math.h>

// Problem constants: B=4, H=W=16, L=256, C=1024, D_INNER=2048, D_STATE=32,
// DT_RANK=64, K=4, NTXT=4096.
//
// Memory plan (d_ws, floats; 60 MB total):
//   A  [0,        4194304)  xz (in_proj out)            live P1..P8; txtnsw P11..P13
//   C  [4194304, 12582912)  32MB multi-use:
//        P0..P1: imgsw_h/l (1M fl), w_insw_h/l (4M fl)
//        P2..P7: xs_hi (4M fl), xs_lo (4M fl)
//        P8..P10: outgsw_h/l (2M fl), w_outsw_h/l (2M fl)
//        P11..P13: enhsw_h/l (1M fl) at C+4194304
//   F  [12582912,13631488)  w_xsw_h/l                   P0..P4
//   H  [13631488,15728640)  ym (atomic merge buf)       P7..P8
// d_out (16 MB = 4M floats) as scratch:
//   px8/xdbl (4M fl) P4..P7;  px4 (4M fl) P10..P11;  final logits P13.

typedef unsigned short u16;
typedef __attribute__((ext_vector_type(8))) short short8;     // 8 bf16 MFMA frag
typedef __attribute__((ext_vector_type(8))) unsigned short ushort8;
typedef __attribute__((ext_vector_type(4))) float f32x4;

__device__ __forceinline__ float sigmoidf_(float x) { return 1.f / (1.f + __expf(-x)); }

__device__ __forceinline__ u16 f2bf(float x) {           // RNE fp32 -> bf16
  unsigned u = __float_as_uint(x);
  unsigned r = u + 0x7FFFu + ((u >> 16) & 1u);
  return (u16)(r >> 16);
}
__device__ __forceinline__ float bf2f(u16 h) { return __uint_as_float((unsigned)h << 16); }

__device__ __forceinline__ void gl_lds16(const u16* g, u16* l) {
  __builtin_amdgcn_global_load_lds((__attribute__((address_space(1))) void*)g,
                                   (__attribute__((address_space(3))) void*)l, 16, 0, 0);
}

// ---------------------------------------------------------------------------
// fp32 (R x Kc, leading dim lda) -> bf16 hi/lo in MFMA staging layout:
// for k-chunk kc (32 wide), row m, group g(0..3): 16B block at ushort offset
//   (kc*R + m)*32 + (g ^ ((m>>1)&3))*8
// holding k-values {kc*32+4g+0..3, kc*32+16+4g+0..3}. This is the exact LDS
// image a GEMM tile needs -> staging is pure linear global_load_lds.
// Element inverse (d = kc*32+dd): dd<16: g=dd>>2, slot=dd&3;
//                                 dd>=16: g=(dd-16)>>2, slot=4+((dd-16)&3).
// ---------------------------------------------------------------------------
__global__ __launch_bounds__(256) void cvt_swz(
    const float* __restrict__ in, u16* __restrict__ hi, u16* __restrict__ lo,
    int R, int bpr /* = Kc/8 */, int lda)
{
  long t = (long)blockIdx.x * 256 + threadIdx.x;
  if (t >= (long)R * bpr) return;
  int m = (int)(t / bpr);
  int rb = (int)(t - (long)m * bpr);
  int kc = rb >> 2, g = rb & 3;
  const float* src = in + (long)m * lda + (kc << 5) + (g << 2);
  float4 a = *(const float4*)src;
  float4 b = *(const float4*)(src + 16);
  float v[8] = {a.x, a.y, a.z, a.w, b.x, b.y, b.z, b.w};
  ushort8 H, L;
#pragma unroll
  for (int q = 0; q < 8; q++) {
    u16 h = f2bf(v[q]);
    H[q] = h;
    L[q] = f2bf(v[q] - bf2f(h));
  }
  long off = (((long)kc * R + m) << 5) + ((long)((g ^ ((m >> 1) & 3)) << 3));
  *(ushort8*)(hi + off) = H;
  *(ushort8*)(lo + off) = L;
}

// ---------------------------------------------------------------------------
// bf16-split MFMA NT GEMM: C[m,n] = sum_k A[m,k]*B[n,k]; operands pre-staged
// as (hi,lo) bf16. acc += Ah*Bh + Ah*Bl + Al*Bh (lo*lo dropped).
// 128x128 tile, BK=32, 4 waves of 64x64. Slot-bijection makes the k->hw-slot
// map correctness-neutral (same staging for A and B).
// Batching: zb=z/ksplit (A rows zb*sArows, B rows (zb%bmod)*sBrows), zk =
// z%ksplit is a K-slice of Ksteps; C += zb*sC + zk*sCk.
// ---------------------------------------------------------------------------
__global__ __launch_bounds__(256) void mfma_nt(
    const u16* __restrict__ Ahi, const u16* __restrict__ Alo,
    const u16* __restrict__ Bhi, const u16* __restrict__ Blo,
    float* __restrict__ C, int Mtot, int Ntot, int Ksteps, int ldc,
    int sArows, int sBrows, int bmod, long sC, long sCk, int ksplit)
{
  __shared__ u16 smem[16384];  // [Ahi|Alo|Bhi|Blo] x 4096 ushorts
  const int tid = threadIdx.x, lane = tid & 63, wid = tid >> 6;
  const int zb = blockIdx.z / ksplit, zk = blockIdx.z - zb * ksplit;
  const int m0 = blockIdx.y << 7, n0 = blockIdx.x << 7;

  const u16* sg;
  long row0;
  int tot;
  if (wid < 2) { row0 = (long)zb * sArows + m0; tot = Mtot; sg = wid ? Alo : Ahi; }
  else         { row0 = (long)(zb % bmod) * sBrows + n0; tot = Ntot; sg = (wid == 3) ? Blo : Bhi; }
  u16* sl = smem + (wid << 12);
  const int laneoff = lane << 3;  // lane*16B (ushorts)

  f32x4 acc[4][4];
#pragma unroll
  for (int i = 0; i < 4; i++)
#pragma unroll
    for (int j = 0; j < 4; j++) acc[i][j] = (f32x4)0.f;

  const int wr = wid >> 1, wc = wid & 1;
  const int fr = lane & 15, g = lane >> 4;
  int offA[4], offB[4];
#pragma unroll
  for (int i = 0; i < 4; i++) {
    int rA = wr * 64 + i * 16 + fr;
    offA[i] = rA * 32 + ((g ^ ((rA >> 1) & 3)) << 3);
    int rB = wc * 64 + i * 16 + fr;
    offB[i] = rB * 32 + ((g ^ ((rB >> 1) & 3)) << 3);
  }

  for (int kc = 0; kc < Ksteps; ++kc) {
    const int kcg = zk * Ksteps + kc;
    const u16* s = sg + ((long)kcg * tot + row0) * 32 + laneoff;
#pragma unroll
    for (int c = 0; c < 8; ++c) gl_lds16(s + c * 512, sl + c * 512 + laneoff);
    asm volatile("s_waitcnt vmcnt(0)" ::: "memory");
    __syncthreads();

    short8 ah[4], al[4], bh[4], bl[4];
#pragma unroll
    for (int i = 0; i < 4; i++) {
      ah[i] = *(const short8*)(smem + offA[i]);
      al[i] = *(const short8*)(smem + 4096 + offA[i]);
      bh[i] = *(const short8*)(smem + 8192 + offB[i]);
      bl[i] = *(const short8*)(smem + 12288 + offB[i]);
    }
#pragma unroll
    for (int i = 0; i < 4; i++)
#pragma unroll
      for (int j = 0; j < 4; j++) {
        acc[i][j] = __builtin_amdgcn_mfma_f32_16x16x32_bf16(ah[i], bh[j], acc[i][j], 0, 0, 0);
        acc[i][j] = __builtin_amdgcn_mfma_f32_16x16x32_bf16(ah[i], bl[j], acc[i][j], 0, 0, 0);
        acc[i][j] = __builtin_amdgcn_mfma_f32_16x16x32_bf16(al[i], bh[j], acc[i][j], 0, 0, 0);
      }
    __syncthreads();
  }

  // C/D layout (HW-verified m89/m91): col = lane&15, row = (lane>>4)*4 + reg
  float* Cb = C + (long)zb * sC + (long)zk * sCk;
  const int r0 = m0 + wr * 64, c0 = n0 + wc * 64;
#pragma unroll
  for (int i = 0; i < 4; i++)
#pragma unroll
    for (int j = 0; j < 4; j++) {
      const long cc = c0 + j * 16 + fr;
#pragma unroll
      for (int q = 0; q < 4; q++)
        Cb[(long)(r0 + i * 16 + g * 4 + q) * ldc + cc] = acc[i][j][q];
    }
}

// ---------------------------------------------------------------------------
__global__ __launch_bounds__(256) void sum8(float* __restrict__ px)
{
  long t = (long)blockIdx.x * 256 + threadIdx.x;
  if (t >= 524288) return;
  float s = px[t];
#pragma unroll
  for (int p = 1; p < 8; p++) s += px[(long)p * 524288 + t];
  px[t] = s;
}

__global__ __launch_bounds__(256) void zero_buf(float4* __restrict__ p)
{
  p[(long)blockIdx.x * 256 + threadIdx.x] = (float4){0.f, 0.f, 0.f, 0.f};
}

// ---------------------------------------------------------------------------
// Depthwise 3x3 conv (SAME) + bias + SiLU; emits the 4 cross-scan copies
// directly as bf16 hi/lo in the MFMA staging layout (rows m = (b*4+k)*256+pos,
// R=4096). This single buffer feeds x_proj's MFMA A-operand AND the scan's u.
// ---------------------------------------------------------------------------
__global__ __launch_bounds__(256) void conv_scatter_bf16(
    const float* __restrict__ xz, const float* __restrict__ cw,
    const float* __restrict__ cb, u16* __restrict__ hi, u16* __restrict__ lo)
{
  const int p = blockIdx.x & 255;
  const int b = blockIdx.x >> 8;
  const int h = p >> 4, w = p & 15;
  const int l1 = (w << 4) + h;
  const int pos[4] = {p, l1, 255 - p, 255 - l1};
#pragma unroll
  for (int it = 0; it < 8; it++) {
    const int d = it * 256 + threadIdx.x;
    float acc = cb[d];
#pragma unroll
    for (int dh = 0; dh < 3; dh++) {
      const int hh = h + dh - 1;
      if (hh < 0 || hh > 15) continue;
#pragma unroll
      for (int dw = 0; dw < 3; dw++) {
        const int ww = w + dw - 1;
        if (ww < 0 || ww > 15) continue;
        acc = fmaf(xz[((long)(b * 256 + (hh << 4) + ww)) * 4096 + d],
                   cw[d * 9 + dh * 3 + dw], acc);
      }
    }
    const float sv = acc * sigmoidf_(acc);
    const u16 hv = f2bf(sv);
    const u16 lv = f2bf(sv - bf2f(hv));
    const int kc = d >> 5, dd = d & 31;
    const int g0 = (dd < 16) ? (dd >> 2) : ((dd - 16) >> 2);
    const int slot = (dd < 16) ? (dd & 3) : 4 + ((dd - 16) & 3);
#pragma unroll
    for (int kk = 0; kk < 4; kk++) {
      const int m = (b * 4 + kk) * 256 + pos[kk];
      const long off = (((long)kc * 4096 + m) << 5) + ((g0 ^ ((m >> 1) & 3)) << 3) + slot;
      hi[off] = hv;
      lo[off] = lv;
    }
  }
}

// ---------------------------------------------------------------------------
// Fused dt_proj + softplus + selective scan + cross-merge (atomicAdd into
// pixel-major ym). 2 lanes per (b,k,d) chain: each holds 16 states and half
// the 64-wide dt dot; pairwise __shfl_xor reduces. All per-step operands are
// staged in LDS per 32-step tile (xdbl rows; u hi/lo from the swizzled buf).
// Grid: (16 d-chunks of 128, K=4, B=4) x 256 threads.
// ---------------------------------------------------------------------------
__global__ __launch_bounds__(256) void scan_fused(
    const u16* __restrict__ xs_hi, const u16* __restrict__ xs_lo,
    const float* __restrict__ xdbl, const float* __restrict__ w_dt,
    const float* __restrict__ b_dt, const float* __restrict__ A_logs,
    const float* __restrict__ Dsv, float* __restrict__ ym)
{
  const int tid = threadIdx.x;
  const int sub = tid & 1;
  const int dl = tid >> 1;                    // 0..127
  const int d = blockIdx.x * 128 + dl;
  const int k = blockIdx.y, b = blockIdx.z;
  const int bk = b * 4 + k;
  const int kd = k * 2048 + d;
  const int n0 = sub * 16;

  float a[16], hst[16];
#pragma unroll
  for (int j = 0; j < 16; j++) {
    a[j] = -__expf(A_logs[(long)kd * 32 + n0 + j]);
    hst[j] = 0.f;
  }
  const float Dval = Dsv[kd];
  const float bias = b_dt[kd];

  float wdt[32];
  const float* wp = w_dt + (long)kd * 64 + sub * 32;
#pragma unroll
  for (int j = 0; j < 32; j += 4) *(float4*)&wdt[j] = *(const float4*)(wp + j);

  // u addressing within the staging layout
  const int dd = d & 31;
  const int g0 = (dd < 16) ? (dd >> 2) : ((dd - 16) >> 2);
  const int slot = (dd < 16) ? (dd & 3) : 4 + ((dd - 16) & 3);
  const int kcl = dl >> 5;                    // local k-chunk 0..3

  const float* xb = xdbl + (long)bk * 256 * 128;
  const int mbase = bk * 256;
  const long obase = (long)b * 256 * 2048 + d;

  __shared__ float xd[32][128];               // xdbl rows: [dt 0..63 | B 64..95 | C 96..127]
  __shared__ u16 uh[4][32][32];               // u hi per (kc, row, 32 ushorts)
  __shared__ u16 ul[4][32][32];

  for (int l0 = 0; l0 < 256; l0 += 32) {
    __syncthreads();
#pragma unroll
    for (int i = 0; i < 4; i++) {
      const int idx = i * 256 + tid;          // 0..1023
      const int r = idx >> 5, c = idx & 31;
      *(float4*)&xd[r][c * 4] = *(const float4*)(xb + (l0 + r) * 128 + c * 4);
    }
#pragma unroll
    for (int i = 0; i < 2; i++) {
      const int j = i * 256 + tid;            // 0..511
      const int kc2 = j >> 7, r = (j >> 2) & 31, part = j & 3;
      const long go = (((long)(blockIdx.x * 4 + kc2) * 4096 + mbase + l0 + r) << 5) + part * 8;
      *(ushort8*)&uh[kc2][r][part * 8] = *(const ushort8*)(xs_hi + go);
      *(ushort8*)&ul[kc2][r][part * 8] = *(const ushort8*)(xs_lo + go);
    }
    __syncthreads();

    for (int ls = 0; ls < 32; ls++) {
      const int l = l0 + ls;
      const int m = mbase + l;
      // dt = softplus(dot64 + bias), split 32+32 across the lane pair
      float da = 0.f;
#pragma unroll
      for (int r4 = 0; r4 < 8; r4++) {
        const float4 xv = *(const float4*)&xd[ls][sub * 32 + r4 * 4];
        da = fmaf(wdt[r4 * 4 + 0], xv.x, da);
        da = fmaf(wdt[r4 * 4 + 1], xv.y, da);
        da = fmaf(wdt[r4 * 4 + 2], xv.z, da);
        da = fmaf(wdt[r4 * 4 + 3], xv.w, da);
      }
      da += __shfl_xor(da, 1);
      const float xsp = da + bias;
      const float dt = (xsp > 20.f) ? xsp : log1pf(__expf(xsp));
      // u from staged bf16 hi+lo
      const int sw = ((g0 ^ ((m >> 1) & 3)) << 3) + slot;
      const float u = bf2f(uh[kcl][ls][sw]) + bf2f(ul[kcl][ls][sw]);
      const float dtu = dt * u;
      float y = 0.f;
#pragma unroll
      for (int j = 0; j < 16; j++) {
        const float dA = __expf(a[j] * dt);
        hst[j] = fmaf(hst[j], dA, dtu * xd[ls][64 + n0 + j]);
        y = fmaf(hst[j], xd[ls][96 + n0 + j], y);
      }
      y += __shfl_xor(y, 1);
      if (sub == 0) {
        int p;
        if (k == 0) p = l;
        else if (k == 1) p = ((l & 15) << 4) + (l >> 4);
        else if (k == 2) p = 255 - l;
        else { const int lr = 255 - l; p = ((lr & 15) << 4) + (lr >> 4); }
        atomicAdd(&ym[obase + (long)p * 2048], fmaf(Dval, u, y));
      }
    }
  }
}

// ---------------------------------------------------------------------------
// LayerNorm(D=2048) over merged ym + SiLU(z) gate -> bf16-split staged write
// (feeds out_proj MFMA A-operand, R=1024 rows).
// ---------------------------------------------------------------------------
__global__ __launch_bounds__(256) void ln_gate_cvt(
    const float* __restrict__ ym, const float* __restrict__ xz,
    const float* __restrict__ lw, const float* __restrict__ lb,
    u16* __restrict__ hi, u16* __restrict__ lo)
{
  const int row = blockIdx.x;
  const int tid = threadIdx.x;
  const float* yr = ym + (long)row * 2048;

  __shared__ float sg[2048];
  __shared__ float sm[8];
  float v[8];
  float s = 0.f, ss = 0.f;
#pragma unroll
  for (int i = 0; i < 8; i++) {
    const float t = yr[i * 256 + tid];
    v[i] = t;
    s += t;
    ss += t * t;
  }
#pragma unroll
  for (int off = 32; off > 0; off >>= 1) {
    s += __shfl_down(s, off);
    ss += __shfl_down(ss, off);
  }
  const int lane = tid & 63, wid = tid >> 6;
  if (lane == 0) { sm[wid] = s; sm[4 + wid] = ss; }
  __syncthreads();
  const float S = sm[0] + sm[1] + sm[2] + sm[3];
  const float SS = sm[4] + sm[5] + sm[6] + sm[7];
  const float mu = S * (1.f / 2048.f);
  const float var = SS * (1.f / 2048.f) - mu * mu;
  const float inv = rsqrtf(var + 1e-5f);
#pragma unroll
  for (int i = 0; i < 8; i++) {
    const int d = i * 256 + tid;
    const float yn = (v[i] - mu) * inv * lw[d] + lb[d];
    const float zz = xz[(long)row * 4096 + 2048 + d];
    sg[d] = yn * zz * sigmoidf_(zz);
  }
  __syncthreads();
  const int kc = tid >> 2, g = tid & 3;       // 64 kc x 4 g = 256 blocks
  const int c0 = kc * 32 + g * 4;
  ushort8 H, L;
#pragma unroll
  for (int q = 0; q < 4; q++) {
    const float f0 = sg[c0 + q], f1 = sg[c0 + 16 + q];
    const u16 h0 = f2bf(f0), h1 = f2bf(f1);
    H[q] = h0; H[4 + q] = h1;
    L[q] = f2bf(f0 - bf2f(h0));
    L[4 + q] = f2bf(f1 - bf2f(h1));
  }
  const long off = (((long)kc * 1024 + row) << 5) + ((long)((g ^ ((row >> 1) & 3)) << 3));
  *(ushort8*)(hi + off) = H;
  *(ushort8*)(lo + off) = L;
}

// ---------------------------------------------------------------------------
// Sum P partials (P=1: plain input) -> row L2-normalize (1024 cols) ->
// bf16-split staged write (R rows).
// ---------------------------------------------------------------------------
template <int P>
__global__ __launch_bounds__(256) void l2cvt(
    const float* __restrict__ in, long pstride,
    u16* __restrict__ hi, u16* __restrict__ lo, int R)
{
  const int row = blockIdx.x;
  const int tid = threadIdx.x;
  __shared__ float sg[1024];
  __shared__ float sm[4];
  float ss = 0.f;
  for (int i = tid; i < 1024; i += 256) {
    float v = in[(long)row * 1024 + i];
#pragma unroll
    for (int p2 = 1; p2 < P; p2++) v += in[(long)p2 * pstride + (long)row * 1024 + i];
    sg[i] = v;
    ss += v * v;
  }
#pragma unroll
  for (int off = 32; off > 0; off >>= 1) ss += __shfl_down(ss, off);
  const int lane = tid & 63, wid = tid >> 6;
  if (lane == 0) sm[wid] = ss;
  __syncthreads();
  const float sc = rsqrtf(sm[0] + sm[1] + sm[2] + sm[3]);
  if (tid < 128) {
    const int kc = tid >> 2, g = tid & 3;     // 32 kc x 4 g
    const int c0 = kc * 32 + g * 4;
    ushort8 H, L;
#pragma unroll
    for (int q = 0; q < 4; q++) {
      const float f0 = sg[c0 + q] * sc, f1 = sg[c0 + 16 + q] * sc;
      const u16 h0 = f2bf(f0), h1 = f2bf(f1);
      H[q] = h0; H[4 + q] = h1;
      L[q] = f2bf(f0 - bf2f(h0));
      L[4 + q] = f2bf(f1 - bf2f(h1));
    }
    const long off = (((long)kc * R + row) << 5) + ((long)((g ^ ((row >> 1) & 3)) << 3));
    *(ushort8*)(hi + off) = H;
    *(ushort8*)(lo + off) = L;
  }
}

// ---------------------------------------------------------------------------
extern "C" void kernel_launch(void* const* d_in, const int* in_sizes, int n_in,
                              void* d_out, int out_size, void* d_ws, size_t ws_size,
                              hipStream_t stream)
{
  const float* img = (const float*)d_in[0];     // (1024,1024) rows=(b,h,w)
  const float* txt = (const float*)d_in[1];     // (4096,1024)
  const float* w_in = (const float*)d_in[2];    // (4096,1024)
  const float* conv_w = (const float*)d_in[3];  // (2048,1,3,3)
  const float* conv_b = (const float*)d_in[4];  // (2048)
  const float* w_x = (const float*)d_in[5];     // (4,128,2048) -> 512 rows
  const float* w_dt = (const float*)d_in[6];    // (4,2048,64)
  const float* b_dt = (const float*)d_in[7];    // (4,2048)
  const float* A_logs = (const float*)d_in[8];  // (8192,32)
  const float* Dsv = (const float*)d_in[9];     // (8192)
  const float* ln_w = (const float*)d_in[10];   // (2048)
  const float* ln_b = (const float*)d_in[11];   // (2048)
  const float* w_out = (const float*)d_in[12];  // (1024,2048)
  float* out = (float*)d_out;                   // (1024,4096) = 4M floats

  // ---- d_ws regions (floats), 60 MB total ----
  float* ws = (float*)d_ws;
  float* xz = ws;                                // A: 4M fl, P1..P8
  float* Cr = ws + 4194304;                      // C: 8M fl, multi-use
  u16* imgsw_h = (u16*)Cr;                       // P0..P1
  u16* imgsw_l = (u16*)(Cr + 524288);
  u16* w_insw_h = (u16*)(Cr + 1048576);
  u16* w_insw_l = (u16*)(Cr + 3145728);
  u16* xs_hi = (u16*)Cr;                         // P2..P7 (8M u16)
  u16* xs_lo = (u16*)(Cr + 4194304);
  u16* outgsw_h = (u16*)Cr;                      // P8..P10
  u16* outgsw_l = (u16*)(Cr + 1048576);
  u16* w_outsw_h = (u16*)(Cr + 2097152);         // P9..P10
  u16* w_outsw_l = (u16*)(Cr + 3145728);
  u16* enhsw_h = (u16*)(Cr + 4194304);           // P11..P13
  u16* enhsw_l = (u16*)(Cr + 4718592);
  u16* w_xsw_h = (u16*)(ws + 12582912);          // F: P0..P4
  u16* w_xsw_l = (u16*)(ws + 13107200);
  float* ym = ws + 13631488;                     // H: 2M fl, P7..P8
  u16* txtnsw_h = (u16*)xz;                      // P11..P13 (xz dead after P8)
  u16* txtnsw_l = (u16*)(xz + 2097152);

  // ---- d_out as scratch (16 MB; dead before final logits write) ----
  float* ob = (float*)d_out;
  float* px8 = ob;                               // P4..P5: 8 x 524288 fl
  float* xdbl = px8;                             // P5..P7: slice 0
  float* px4 = ob;                               // P10..P11: 4 x 1M fl

  // P0: convert weights/inputs to staged bf16 hi/lo
  cvt_swz<<<512, 256, 0, stream>>>(img, imgsw_h, imgsw_l, 1024, 128, 1024);
  cvt_swz<<<2048, 256, 0, stream>>>(w_in, w_insw_h, w_insw_l, 4096, 128, 1024);
  cvt_swz<<<512, 256, 0, stream>>>(w_x, w_xsw_h, w_xsw_l, 512, 256, 2048);

  // P1: in_proj  xz = img @ w_in^T   (1024 x 4096 x 1024)
  mfma_nt<<<dim3(32, 8, 1), 256, 0, stream>>>(imgsw_h, imgsw_l, w_insw_h, w_insw_l,
                                              xz, 1024, 4096, 32, 4096, 0, 0, 1, 0, 0, 1);

  // P2: depthwise conv + SiLU + cross-scan scatter -> xs hi/lo (staged layout)
  conv_scatter_bf16<<<dim3(1024), 256, 0, stream>>>(xz, conv_w, conv_b, xs_hi, xs_lo);

  // P4: x_proj (16 batches, K-split 8) -> px8[zk][bk][256][128]
  mfma_nt<<<dim3(1, 2, 128), 256, 0, stream>>>(xs_hi, xs_lo, w_xsw_h, w_xsw_l,
                                               px8, 4096, 512, 8, 128, 256, 128, 4,
                                               32768, 524288, 8);
  // P5: reduce K-split -> xdbl (slice 0 in place); zero merge buffer
  sum8<<<2048, 256, 0, stream>>>(px8);
  zero_buf<<<2048, 256, 0, stream>>>((float4*)ym);

  // P7: fused dt_proj + selective scan + cross-merge (atomic) -> ym
  scan_fused<<<dim3(16, 4, 4), 256, 0, stream>>>(xs_hi, xs_lo, xdbl, w_dt, b_dt,
                                                 A_logs, Dsv, ym);

  // P8: LayerNorm + SiLU gate -> outgsw (staged bf16)
  ln_gate_cvt<<<dim3(1024), 256, 0, stream>>>(ym, xz, ln_w, ln_b, outgsw_h, outgsw_l);

  // P9: convert w_out
  cvt_swz<<<1024, 256, 0, stream>>>(w_out, w_outsw_h, w_outsw_l, 1024, 256, 2048);

  // P10: out_proj (K-split 4) -> px4 partials in d_out
  mfma_nt<<<dim3(8, 8, 4), 256, 0, stream>>>(outgsw_h, outgsw_l, w_outsw_h, w_outsw_l,
                                             px4, 1024, 1024, 16, 1024, 0, 0, 1,
                                             0, 1048576, 4);

  // P11: sum + L2-normalize + stage (image rows; text rows)
  l2cvt<4><<<dim3(1024), 256, 0, stream>>>(px4, 1048576, enhsw_h, enhsw_l, 1024);
  l2cvt<1><<<dim3(4096), 256, 0, stream>>>(txt, 0, txtnsw_h, txtnsw_l, 4096);

  // P13: logits = enh_n @ txt_n^T  (1024 x 4096 x 1024) -> d_out
  mfma_nt<<<dim3(32, 8, 1), 256, 0, stream>>>(enhsw_h, enhsw_l, txtnsw_h, txtnsw_l,
                                              out, 1024, 4096, 32, 4096, 0, 0, 1, 0, 0, 1);
}

// Round 5
// 434.389 us; speedup vs baseline: 1.2057x; 1.2057x over previous
//
#include <hip/hip_runtime.h>
#include <math.h>

// Problem constants: B=4, H=W=16, L=256, C=1024, D_INNER=2048, D_STATE=32,
// DT_RANK=64, K=4, NTXT=4096.
//
// Memory plan (d_ws, floats; 60 MB total):
//   A  [0,        4194304)  xz (in_proj out)            live P1..P8; txtnsw P11..P13
//   C  [4194304, 12582912)  32MB multi-use:
//        P0..P1: imgsw_h/l (1M fl), w_insw_h/l (4M fl)
//        P2..P7: xs_hi (4M fl), xs_lo (4M fl)
//        P8..P10: outgsw_h/l (2M fl), w_outsw_h/l (2M fl)
//        P11..P13: enhsw_h/l (1M fl) at C+4194304
//   F  [12582912,13631488)  w_xsw_h/l                   P0..P4
//   H  [13631488,15728640)  ym (atomic merge buf)       P7..P8
// d_out (16 MB = 4M floats) as scratch:
//   px8/xdbl (4M fl) P4..P7;  px4 (4M fl) P10..P11;  final logits P13.

typedef unsigned short u16;
typedef __attribute__((ext_vector_type(8))) short short8;     // 8 bf16 MFMA frag
typedef __attribute__((ext_vector_type(8))) unsigned short ushort8;
typedef __attribute__((ext_vector_type(4))) float f32x4;

__device__ __forceinline__ float sigmoidf_(float x) { return 1.f / (1.f + __expf(-x)); }

__device__ __forceinline__ u16 f2bf(float x) {           // RNE fp32 -> bf16
  unsigned u = __float_as_uint(x);
  unsigned r = u + 0x7FFFu + ((u >> 16) & 1u);
  return (u16)(r >> 16);
}
__device__ __forceinline__ float bf2f(u16 h) { return __uint_as_float((unsigned)h << 16); }

__device__ __forceinline__ void gl_lds16(const u16* g, u16* l) {
  __builtin_amdgcn_global_load_lds((__attribute__((address_space(1))) void*)g,
                                   (__attribute__((address_space(3))) void*)l, 16, 0, 0);
}

// ---------------------------------------------------------------------------
// fp32 (R x Kc, leading dim lda) -> bf16 hi/lo in MFMA staging layout:
// for k-chunk kc (32 wide), row m, group g(0..3): 16B block at ushort offset
//   (kc*R + m)*32 + (g ^ ((m>>1)&3))*8
// holding k-values {kc*32+4g+0..3, kc*32+16+4g+0..3}.
// ---------------------------------------------------------------------------
__global__ __launch_bounds__(256) void cvt_swz(
    const float* __restrict__ in, u16* __restrict__ hi, u16* __restrict__ lo,
    int R, int bpr /* = Kc/8 */, int lda)
{
  long t = (long)blockIdx.x * 256 + threadIdx.x;
  if (t >= (long)R * bpr) return;
  int m = (int)(t / bpr);
  int rb = (int)(t - (long)m * bpr);
  int kc = rb >> 2, g = rb & 3;
  const float* src = in + (long)m * lda + (kc << 5) + (g << 2);
  float4 a = *(const float4*)src;
  float4 b = *(const float4*)(src + 16);
  float v[8] = {a.x, a.y, a.z, a.w, b.x, b.y, b.z, b.w};
  ushort8 H, L;
#pragma unroll
  for (int q = 0; q < 8; q++) {
    u16 h = f2bf(v[q]);
    H[q] = h;
    L[q] = f2bf(v[q] - bf2f(h));
  }
  long off = (((long)kc * R + m) << 5) + ((long)((g ^ ((m >> 1) & 3)) << 3));
  *(ushort8*)(hi + off) = H;
  *(ushort8*)(lo + off) = L;
}

// ---------------------------------------------------------------------------
// bf16-split MFMA NT GEMM (proven round 4): C[m,n] = sum_k A[m,k]*B[n,k].
// ---------------------------------------------------------------------------
__global__ __launch_bounds__(256) void mfma_nt(
    const u16* __restrict__ Ahi, const u16* __restrict__ Alo,
    const u16* __restrict__ Bhi, const u16* __restrict__ Blo,
    float* __restrict__ C, int Mtot, int Ntot, int Ksteps, int ldc,
    int sArows, int sBrows, int bmod, long sC, long sCk, int ksplit)
{
  __shared__ u16 smem[16384];  // [Ahi|Alo|Bhi|Blo] x 4096 ushorts
  const int tid = threadIdx.x, lane = tid & 63, wid = tid >> 6;
  const int zb = blockIdx.z / ksplit, zk = blockIdx.z - zb * ksplit;
  const int m0 = blockIdx.y << 7, n0 = blockIdx.x << 7;

  const u16* sg;
  long row0;
  int tot;
  if (wid < 2) { row0 = (long)zb * sArows + m0; tot = Mtot; sg = wid ? Alo : Ahi; }
  else         { row0 = (long)(zb % bmod) * sBrows + n0; tot = Ntot; sg = (wid == 3) ? Blo : Bhi; }
  u16* sl = smem + (wid << 12);
  const int laneoff = lane << 3;  // lane*16B (ushorts)

  f32x4 acc[4][4];
#pragma unroll
  for (int i = 0; i < 4; i++)
#pragma unroll
    for (int j = 0; j < 4; j++) acc[i][j] = (f32x4)0.f;

  const int wr = wid >> 1, wc = wid & 1;
  const int fr = lane & 15, g = lane >> 4;
  int offA[4], offB[4];
#pragma unroll
  for (int i = 0; i < 4; i++) {
    int rA = wr * 64 + i * 16 + fr;
    offA[i] = rA * 32 + ((g ^ ((rA >> 1) & 3)) << 3);
    int rB = wc * 64 + i * 16 + fr;
    offB[i] = rB * 32 + ((g ^ ((rB >> 1) & 3)) << 3);
  }

  for (int kc = 0; kc < Ksteps; ++kc) {
    const int kcg = zk * Ksteps + kc;
    const u16* s = sg + ((long)kcg * tot + row0) * 32 + laneoff;
#pragma unroll
    for (int c = 0; c < 8; ++c) gl_lds16(s + c * 512, sl + c * 512 + laneoff);
    asm volatile("s_waitcnt vmcnt(0)" ::: "memory");
    __syncthreads();

    short8 ah[4], al[4], bh[4], bl[4];
#pragma unroll
    for (int i = 0; i < 4; i++) {
      ah[i] = *(const short8*)(smem + offA[i]);
      al[i] = *(const short8*)(smem + 4096 + offA[i]);
      bh[i] = *(const short8*)(smem + 8192 + offB[i]);
      bl[i] = *(const short8*)(smem + 12288 + offB[i]);
    }
#pragma unroll
    for (int i = 0; i < 4; i++)
#pragma unroll
      for (int j = 0; j < 4; j++) {
        acc[i][j] = __builtin_amdgcn_mfma_f32_16x16x32_bf16(ah[i], bh[j], acc[i][j], 0, 0, 0);
        acc[i][j] = __builtin_amdgcn_mfma_f32_16x16x32_bf16(ah[i], bl[j], acc[i][j], 0, 0, 0);
        acc[i][j] = __builtin_amdgcn_mfma_f32_16x16x32_bf16(al[i], bh[j], acc[i][j], 0, 0, 0);
      }
    __syncthreads();
  }

  // C/D layout (HW-verified m89/m91): col = lane&15, row = (lane>>4)*4 + reg
  float* Cb = C + (long)zb * sC + (long)zk * sCk;
  const int r0 = m0 + wr * 64, c0 = n0 + wc * 64;
#pragma unroll
  for (int i = 0; i < 4; i++)
#pragma unroll
    for (int j = 0; j < 4; j++) {
      const long cc = c0 + j * 16 + fr;
#pragma unroll
      for (int q = 0; q < 4; q++)
        Cb[(long)(r0 + i * 16 + g * 4 + q) * ldc + cc] = acc[i][j][q];
    }
}

// ---------------------------------------------------------------------------
__global__ __launch_bounds__(256) void sum8(float* __restrict__ px)
{
  long t = (long)blockIdx.x * 256 + threadIdx.x;
  if (t >= 524288) return;
  float s = px[t];
#pragma unroll
  for (int p = 1; p < 8; p++) s += px[(long)p * 524288 + t];
  px[t] = s;
}

__global__ __launch_bounds__(256) void zero_buf(float4* __restrict__ p)
{
  p[(long)blockIdx.x * 256 + threadIdx.x] = (float4){0.f, 0.f, 0.f, 0.f};
}

// ---------------------------------------------------------------------------
// Depthwise 3x3 conv (SAME) + bias + SiLU; emits 4 cross-scan copies as bf16
// hi/lo in the MFMA staging layout (rows m = (b*4+k)*256+pos, R=4096).
// ---------------------------------------------------------------------------
__global__ __launch_bounds__(256) void conv_scatter_bf16(
    const float* __restrict__ xz, const float* __restrict__ cw,
    const float* __restrict__ cb, u16* __restrict__ hi, u16* __restrict__ lo)
{
  const int p = blockIdx.x & 255;
  const int b = blockIdx.x >> 8;
  const int h = p >> 4, w = p & 15;
  const int l1 = (w << 4) + h;
  const int pos[4] = {p, l1, 255 - p, 255 - l1};
#pragma unroll
  for (int it = 0; it < 8; it++) {
    const int d = it * 256 + threadIdx.x;
    float acc = cb[d];
#pragma unroll
    for (int dh = 0; dh < 3; dh++) {
      const int hh = h + dh - 1;
      if (hh < 0 || hh > 15) continue;
#pragma unroll
      for (int dw = 0; dw < 3; dw++) {
        const int ww = w + dw - 1;
        if (ww < 0 || ww > 15) continue;
        acc = fmaf(xz[((long)(b * 256 + (hh << 4) + ww)) * 4096 + d],
                   cw[d * 9 + dh * 3 + dw], acc);
      }
    }
    const float sv = acc * sigmoidf_(acc);
    const u16 hv = f2bf(sv);
    const u16 lv = f2bf(sv - bf2f(hv));
    const int kc = d >> 5, dd = d & 31;
    const int g0 = (dd < 16) ? (dd >> 2) : ((dd - 16) >> 2);
    const int slot = (dd < 16) ? (dd & 3) : 4 + ((dd - 16) & 3);
#pragma unroll
    for (int kk = 0; kk < 4; kk++) {
      const int m = (b * 4 + kk) * 256 + pos[kk];
      const long off = (((long)kc * 4096 + m) << 5) + ((g0 ^ ((m >> 1) & 3)) << 3) + slot;
      hi[off] = hv;
      lo[off] = lv;
    }
  }
}

// ---------------------------------------------------------------------------
// Scan v2: fused dt_proj + softplus + selective scan + cross-merge (atomic).
// Block = 256 threads = 64 chains x 4 lanes (8 states each). Grid (32,4,4)
// = 512 blocks -> 2 blocks/CU -> 2 waves/SIMD.
// Per 32-step tile: [stage xd rows + decode u -> LDS] -> [parallel dt phase:
// each lane keeps its chain's w_dt row (64 VGPR); all 64 lanes read the SAME
// xd[ls][c] address (LDS broadcast = free) -> 512 indep FMAs/thread] ->
// [serial 32 steps: 8 exp + 16 FMA per thread, 2 shfl_xor y-reduce].
// ---------------------------------------------------------------------------
__global__ __launch_bounds__(256) void scan_fused(
    const u16* __restrict__ xs_hi, const u16* __restrict__ xs_lo,
    const float* __restrict__ xdbl, const float* __restrict__ w_dt,
    const float* __restrict__ b_dt, const float* __restrict__ A_logs,
    const float* __restrict__ Dsv, float* __restrict__ ym)
{
  const int tid = threadIdx.x;
  const int k = blockIdx.y, b = blockIdx.z;
  const int bk = b * 4 + k;
  const int dbase = blockIdx.x << 6;          // 64-chain d-chunk
  const int mbase = bk * 256;
  const int kc0 = dbase >> 5;                 // first of 2 global k-chunks

  // ---- scan-phase identity: chain dc = tid>>2, sub = tid&3, states n0..n0+7
  const int dc = tid >> 2, sub = tid & 3;
  const int d = dbase + dc;
  const int kd = k * 2048 + d;
  const int n0 = sub * 8;

  float a[8], hst[8];
#pragma unroll
  for (int j = 0; j < 8; j++) {
    a[j] = -__expf(A_logs[(long)kd * 32 + n0 + j]);
    hst[j] = 0.f;
  }
  const float Dval = Dsv[kd];
  const long obase = (long)b * 256 * 2048 + d;

  // ---- dot-phase identity: chain lam = tid&63, wave wv handles ls wv*8..+7
  const int lam = tid & 63, wv = tid >> 6;
  const int kdd = k * 2048 + dbase + lam;
  float wdt[64];
  const float* wp = w_dt + (long)kdd * 64;
#pragma unroll
  for (int c = 0; c < 64; c += 4) *(float4*)&wdt[c] = *(const float4*)(wp + c);
  const float bdt = b_dt[kdd];

  const float* xb = xdbl + (long)bk * 256 * 128;

  __shared__ float xd[32][128];   // xdbl rows: [dt-in 0..63 | B 64..95 | C 96..127]
  __shared__ float dtS[32][64];
  __shared__ float uS[32][64];

  for (int l0 = 0; l0 < 256; l0 += 32) {
    __syncthreads();              // previous tile fully consumed
    // stage xd (32 rows x 128 floats)
#pragma unroll
    for (int i = 0; i < 4; i++) {
      const int idx = i * 256 + tid;
      const int r = idx >> 5, c = idx & 31;
      *(float4*)&xd[r][c * 4] = *(const float4*)(xb + (l0 + r) * 128 + c * 4);
    }
    // stage + decode u: thread -> (r, kcl, part); 8 u16 each from hi and lo
    {
      const int r = tid >> 3, kcl = (tid >> 2) & 1, part = tid & 3;
      const int m = mbase + l0 + r;
      const long go = (((long)(kc0 + kcl) * 4096 + m) << 5) + part * 8;
      const ushort8 Hv = *(const ushort8*)(xs_hi + go);
      const ushort8 Lv = *(const ushort8*)(xs_lo + go);
      const int gx = part ^ ((m >> 1) & 3);
      float lo4[4], hi4[4];
#pragma unroll
      for (int q = 0; q < 4; q++) {
        lo4[q] = bf2f(Hv[q]) + bf2f(Lv[q]);          // dd = gx*4+q
        hi4[q] = bf2f(Hv[4 + q]) + bf2f(Lv[4 + q]);  // dd = 16+gx*4+q
      }
      *(float4*)&uS[r][kcl * 32 + gx * 4] = *(float4*)lo4;
      *(float4*)&uS[r][kcl * 32 + 16 + gx * 4] = *(float4*)hi4;
    }
    __syncthreads();
    // parallel dt phase: 8 dots of 64 per thread, xd reads are wave-broadcast
#pragma unroll
    for (int s = 0; s < 8; s++) {
      const int ls = wv * 8 + s;
      float acc = 0.f;
#pragma unroll
      for (int c4 = 0; c4 < 16; c4++) {
        const float4 xv = *(const float4*)&xd[ls][c4 * 4];
        acc = fmaf(wdt[c4 * 4 + 0], xv.x, acc);
        acc = fmaf(wdt[c4 * 4 + 1], xv.y, acc);
        acc = fmaf(wdt[c4 * 4 + 2], xv.z, acc);
        acc = fmaf(wdt[c4 * 4 + 3], xv.w, acc);
      }
      const float xsp = acc + bdt;
      dtS[ls][lam] = (xsp > 20.f) ? xsp : log1pf(__expf(xsp));
    }
    __syncthreads();
    // serial scan over the 32 staged steps
#pragma unroll 4
    for (int ls = 0; ls < 32; ls++) {
      const int l = l0 + ls;
      const float dt = dtS[ls][dc];
      const float u = uS[ls][dc];
      const float dtu = dt * u;
      float y = 0.f;
#pragma unroll
      for (int j = 0; j < 8; j++) {
        const float dA = __expf(a[j] * dt);
        hst[j] = fmaf(hst[j], dA, dtu * xd[ls][64 + n0 + j]);
        y = fmaf(hst[j], xd[ls][96 + n0 + j], y);
      }
      y += __shfl_xor(y, 1);
      y += __shfl_xor(y, 2);
      if (sub == 0) {
        int p;
        if (k == 0) p = l;
        else if (k == 1) p = ((l & 15) << 4) + (l >> 4);
        else if (k == 2) p = 255 - l;
        else { const int lr = 255 - l; p = ((lr & 15) << 4) + (lr >> 4); }
        atomicAdd(&ym[obase + (long)p * 2048], fmaf(Dval, u, y));
      }
    }
  }
}

// ---------------------------------------------------------------------------
// LayerNorm(D=2048) over merged ym + SiLU(z) gate -> bf16-split staged write.
// ---------------------------------------------------------------------------
__global__ __launch_bounds__(256) void ln_gate_cvt(
    const float* __restrict__ ym, const float* __restrict__ xz,
    const float* __restrict__ lw, const float* __restrict__ lb,
    u16* __restrict__ hi, u16* __restrict__ lo)
{
  const int row = blockIdx.x;
  const int tid = threadIdx.x;
  const float* yr = ym + (long)row * 2048;

  __shared__ float sg[2048];
  __shared__ float sm[8];
  float v[8];
  float s = 0.f, ss = 0.f;
#pragma unroll
  for (int i = 0; i < 8; i++) {
    const float t = yr[i * 256 + tid];
    v[i] = t;
    s += t;
    ss += t * t;
  }
#pragma unroll
  for (int off = 32; off > 0; off >>= 1) {
    s += __shfl_down(s, off);
    ss += __shfl_down(ss, off);
  }
  const int lane = tid & 63, wid = tid >> 6;
  if (lane == 0) { sm[wid] = s; sm[4 + wid] = ss; }
  __syncthreads();
  const float S = sm[0] + sm[1] + sm[2] + sm[3];
  const float SS = sm[4] + sm[5] + sm[6] + sm[7];
  const float mu = S * (1.f / 2048.f);
  const float var = SS * (1.f / 2048.f) - mu * mu;
  const float inv = rsqrtf(var + 1e-5f);
#pragma unroll
  for (int i = 0; i < 8; i++) {
    const int d = i * 256 + tid;
    const float yn = (v[i] - mu) * inv * lw[d] + lb[d];
    const float zz = xz[(long)row * 4096 + 2048 + d];
    sg[d] = yn * zz * sigmoidf_(zz);
  }
  __syncthreads();
  const int kc = tid >> 2, g = tid & 3;       // 64 kc x 4 g = 256 blocks
  const int c0 = kc * 32 + g * 4;
  ushort8 H, L;
#pragma unroll
  for (int q = 0; q < 4; q++) {
    const float f0 = sg[c0 + q], f1 = sg[c0 + 16 + q];
    const u16 h0 = f2bf(f0), h1 = f2bf(f1);
    H[q] = h0; H[4 + q] = h1;
    L[q] = f2bf(f0 - bf2f(h0));
    L[4 + q] = f2bf(f1 - bf2f(h1));
  }
  const long off = (((long)kc * 1024 + row) << 5) + ((long)((g ^ ((row >> 1) & 3)) << 3));
  *(ushort8*)(hi + off) = H;
  *(ushort8*)(lo + off) = L;
}

// ---------------------------------------------------------------------------
// Sum P partials (P=1: plain input) -> row L2-normalize (1024 cols) ->
// bf16-split staged write (R rows).
// ---------------------------------------------------------------------------
template <int P>
__global__ __launch_bounds__(256) void l2cvt(
    const float* __restrict__ in, long pstride,
    u16* __restrict__ hi, u16* __restrict__ lo, int R)
{
  const int row = blockIdx.x;
  const int tid = threadIdx.x;
  __shared__ float sg[1024];
  __shared__ float sm[4];
  float ss = 0.f;
  for (int i = tid; i < 1024; i += 256) {
    float v = in[(long)row * 1024 + i];
#pragma unroll
    for (int p2 = 1; p2 < P; p2++) v += in[(long)p2 * pstride + (long)row * 1024 + i];
    sg[i] = v;
    ss += v * v;
  }
#pragma unroll
  for (int off = 32; off > 0; off >>= 1) ss += __shfl_down(ss, off);
  const int lane = tid & 63, wid = tid >> 6;
  if (lane == 0) sm[wid] = ss;
  __syncthreads();
  const float sc = rsqrtf(sm[0] + sm[1] + sm[2] + sm[3]);
  if (tid < 128) {
    const int kc = tid >> 2, g = tid & 3;     // 32 kc x 4 g
    const int c0 = kc * 32 + g * 4;
    ushort8 H, L;
#pragma unroll
    for (int q = 0; q < 4; q++) {
      const float f0 = sg[c0 + q] * sc, f1 = sg[c0 + 16 + q] * sc;
      const u16 h0 = f2bf(f0), h1 = f2bf(f1);
      H[q] = h0; H[4 + q] = h1;
      L[q] = f2bf(f0 - bf2f(h0));
      L[4 + q] = f2bf(f1 - bf2f(h1));
    }
    const long off = (((long)kc * R + row) << 5) + ((long)((g ^ ((row >> 1) & 3)) << 3));
    *(ushort8*)(hi + off) = H;
    *(ushort8*)(lo + off) = L;
  }
}

// ---------------------------------------------------------------------------
extern "C" void kernel_launch(void* const* d_in, const int* in_sizes, int n_in,
                              void* d_out, int out_size, void* d_ws, size_t ws_size,
                              hipStream_t stream)
{
  const float* img = (const float*)d_in[0];     // (1024,1024) rows=(b,h,w)
  const float* txt = (const float*)d_in[1];     // (4096,1024)
  const float* w_in = (const float*)d_in[2];    // (4096,1024)
  const float* conv_w = (const float*)d_in[3];  // (2048,1,3,3)
  const float* conv_b = (const float*)d_in[4];  // (2048)
  const float* w_x = (const float*)d_in[5];     // (4,128,2048) -> 512 rows
  const float* w_dt = (const float*)d_in[6];    // (4,2048,64)
  const float* b_dt = (const float*)d_in[7];    // (4,2048)
  const float* A_logs = (const float*)d_in[8];  // (8192,32)
  const float* Dsv = (const float*)d_in[9];     // (8192)
  const float* ln_w = (const float*)d_in[10];   // (2048)
  const float* ln_b = (const float*)d_in[11];   // (2048)
  const float* w_out = (const float*)d_in[12];  // (1024,2048)
  float* out = (float*)d_out;                   // (1024,4096) = 4M floats

  // ---- d_ws regions (floats), 60 MB total ----
  float* ws = (float*)d_ws;
  float* xz = ws;                                // A: 4M fl, P1..P8
  float* Cr = ws + 4194304;                      // C: 8M fl, multi-use
  u16* imgsw_h = (u16*)Cr;                       // P0..P1
  u16* imgsw_l = (u16*)(Cr + 524288);
  u16* w_insw_h = (u16*)(Cr + 1048576);
  u16* w_insw_l = (u16*)(Cr + 3145728);
  u16* xs_hi = (u16*)Cr;                         // P2..P7 (8M u16)
  u16* xs_lo = (u16*)(Cr + 4194304);
  u16* outgsw_h = (u16*)Cr;                      // P8..P10
  u16* outgsw_l = (u16*)(Cr + 1048576);
  u16* w_outsw_h = (u16*)(Cr + 2097152);         // P9..P10
  u16* w_outsw_l = (u16*)(Cr + 3145728);
  u16* enhsw_h = (u16*)(Cr + 4194304);           // P11..P13
  u16* enhsw_l = (u16*)(Cr + 4718592);
  u16* w_xsw_h = (u16*)(ws + 12582912);          // F: P0..P4
  u16* w_xsw_l = (u16*)(ws + 13107200);
  float* ym = ws + 13631488;                     // H: 2M fl, P7..P8
  u16* txtnsw_h = (u16*)xz;                      // P11..P13 (xz dead after P8)
  u16* txtnsw_l = (u16*)(xz + 2097152);

  // ---- d_out as scratch (16 MB; dead before final logits write) ----
  float* ob = (float*)d_out;
  float* px8 = ob;                               // P4..P5: 8 x 524288 fl
  float* xdbl = px8;                             // P5..P7: slice 0
  float* px4 = ob;                               // P10..P11: 4 x 1M fl

  // P0: convert weights/inputs to staged bf16 hi/lo
  cvt_swz<<<512, 256, 0, stream>>>(img, imgsw_h, imgsw_l, 1024, 128, 1024);
  cvt_swz<<<2048, 256, 0, stream>>>(w_in, w_insw_h, w_insw_l, 4096, 128, 1024);
  cvt_swz<<<512, 256, 0, stream>>>(w_x, w_xsw_h, w_xsw_l, 512, 256, 2048);

  // P1: in_proj  xz = img @ w_in^T   (1024 x 4096 x 1024)
  mfma_nt<<<dim3(32, 8, 1), 256, 0, stream>>>(imgsw_h, imgsw_l, w_insw_h, w_insw_l,
                                              xz, 1024, 4096, 32, 4096, 0, 0, 1, 0, 0, 1);

  // P2: depthwise conv + SiLU + cross-scan scatter -> xs hi/lo (staged layout)
  conv_scatter_bf16<<<dim3(1024), 256, 0, stream>>>(xz, conv_w, conv_b, xs_hi, xs_lo);

  // P4: x_proj (16 batches, K-split 8) -> px8[zk][bk][256][128]
  mfma_nt<<<dim3(1, 2, 128), 256, 0, stream>>>(xs_hi, xs_lo, w_xsw_h, w_xsw_l,
                                               px8, 4096, 512, 8, 128, 256, 128, 4,
                                               32768, 524288, 8);
  // P5: reduce K-split -> xdbl (slice 0 in place); zero merge buffer
  sum8<<<2048, 256, 0, stream>>>(px8);
  zero_buf<<<2048, 256, 0, stream>>>((float4*)ym);

  // P7: fused dt_proj + selective scan + cross-merge (atomic) -> ym
  scan_fused<<<dim3(32, 4, 4), 256, 0, stream>>>(xs_hi, xs_lo, xdbl, w_dt, b_dt,
                                                 A_logs, Dsv, ym);

  // P8: LayerNorm + SiLU gate -> outgsw (staged bf16)
  ln_gate_cvt<<<dim3(1024), 256, 0, stream>>>(ym, xz, ln_w, ln_b, outgsw_h, outgsw_l);

  // P9: convert w_out
  cvt_swz<<<1024, 256, 0, stream>>>(w_out, w_outsw_h, w_outsw_l, 1024, 256, 2048);

  // P10: out_proj (K-split 4) -> px4 partials in d_out
  mfma_nt<<<dim3(8, 8, 4), 256, 0, stream>>>(outgsw_h, outgsw_l, w_outsw_h, w_outsw_l,
                                             px4, 1024, 1024, 16, 1024, 0, 0, 1,
                                             0, 1048576, 4);

  // P11: sum + L2-normalize + stage (image rows; text rows)
  l2cvt<4><<<dim3(1024), 256, 0, stream>>>(px4, 1048576, enhsw_h, enhsw_l, 1024);
  l2cvt<1><<<dim3(4096), 256, 0, stream>>>(txt, 0, txtnsw_h, txtnsw_l, 4096);

  // P13: logits = enh_n @ txt_n^T  (1024 x 4096 x 1024) -> d_out
  mfma_nt<<<dim3(32, 8, 1), 256, 0, stream>>>(enhsw_h, enhsw_l, txtnsw_h, txtnsw_l,
                                              out, 1024, 4096, 32, 4096, 0, 0, 1, 0, 0, 1);
}